// Round 13
// baseline (153.842 us; speedup 1.0000x reference)
//
#include <hip/hip_runtime.h>
#include <cstdint>
#include <cstddef>

#define NN 50000
#define IN_CH 128
#define C1 256        // HEADS*HID
#define HID 64
#define HEADS 4
#define OUT_CH 16
#define NEG_SLOPE 0.2f
#define EPS_SM 1e-16f
#define NEGINF -3.4e38f
#define NBUK ((NN + 255) >> 8)   // 196 buckets of 256 dst nodes
#define BCAP 4864                // bucket capacity: mean 4352 + 8 sigma
#define NGEMM1 ((NN + 63) / 64)  // 782

typedef __attribute__((ext_vector_type(8))) short bf16x8;
typedef __attribute__((ext_vector_type(4))) float f32x4;

__device__ __forceinline__ unsigned short f2b(float f) {
    unsigned int u = __float_as_uint(f);
    u += 0x7fffu + ((u >> 16) & 1u);   // round-to-nearest-even
    return (unsigned short)(u >> 16);
}
__device__ __forceinline__ float b2f_lo(unsigned int packed) {
    return __uint_as_float(packed << 16);
}
__device__ __forceinline__ float b2f_hi(unsigned int packed) {
    return __uint_as_float(packed & 0xffff0000u);
}

// ===== launch 2: bucket_scatter (blocks 0..255) ∥ cvt_weights (256..400) ====
// bcursor is zero-initialized; bases b*BCAP added locally.
__global__ __launch_bounds__(256) void fused_scatter_cvt(
        const int* __restrict__ src_arr, const int* __restrict__ dst_arr,
        int* __restrict__ bcursor, unsigned int* __restrict__ ebuf,
        int Etot, int E,
        const float* __restrict__ W1, const float* __restrict__ W2,
        const float* __restrict__ a_src1, const float* __restrict__ a_dst1,
        unsigned short* __restrict__ w1t, unsigned short* __restrict__ w2b,
        unsigned short* __restrict__ waSDt) {
    __shared__ int cnt[NBUK];
    __shared__ int cur[NBUK];
    int t = threadIdx.x;
    if (blockIdx.x < 256) {
        int bid = blockIdx.x;
        for (int i = t; i < NBUK; i += 256) cnt[i] = 0;
        __syncthreads();
        for (int i = bid * 256 + t; i < Etot; i += 65536) {
            int dst = (i < E) ? dst_arr[i] : (i - E);
            atomicAdd(&cnt[dst >> 8], 1);
        }
        __syncthreads();
        for (int i = t; i < NBUK; i += 256)
            cur[i] = i * BCAP + (cnt[i] ? atomicAdd(&bcursor[i], cnt[i]) : 0);
        __syncthreads();
        for (int i = bid * 256 + t; i < Etot; i += 65536) {
            int dst, src;
            if (i < E) { dst = dst_arr[i]; src = src_arr[i]; }
            else { dst = i - E; src = i - E; }
            int buk = dst >> 8;
            int pos = atomicAdd(&cur[buk], 1);
            if (pos < (buk + 1) * BCAP)   // 8-sigma guard, never expected
                ebuf[pos] = ((unsigned int)(dst & 255) << 16) | (unsigned int)src;
        }
    } else {
        int b = blockIdx.x - 256;
        if (b < 128) {
            w1t[t * 128 + b] = f2b(W1[b * 256 + t]);
        } else if (b < 144) {
            int k = (b - 128) * 16 + (t >> 4);
            int c = t & 15;
            w2b[c * 256 + k] = f2b(W2[k * 16 + c]);
        } else {
            if (t < 128) {
                const float* wrow = W1 + t * 256;
#pragma unroll
                for (int h = 0; h < 4; ++h) {
                    float ss = 0.f, sd = 0.f;
#pragma unroll
                    for (int c = 0; c < 64; ++c) {
                        float w = wrow[h * 64 + c];
                        ss += w * a_src1[h * 64 + c];
                        sd += w * a_dst1[h * 64 + c];
                    }
                    waSDt[h * 128 + t] = f2b(ss);
                    waSDt[(4 + h) * 128 + t] = f2b(sd);
                }
#pragma unroll
                for (int c = 8; c < 16; ++c) waSDt[c * 128 + t] = 0;
            }
        }
    }
}

// ===== launch 3: bucket_csr (blocks 0..195) ∥ gemm1 (196..977) ==============
__global__ __launch_bounds__(256) void fused_csr_gemm1(
        const unsigned int* __restrict__ ebuf, const int* __restrict__ bcursor,
        int* __restrict__ rowst, int* __restrict__ rowend, int* __restrict__ srcs,
        const float* __restrict__ X,
        const unsigned short* __restrict__ w1t,
        const unsigned short* __restrict__ waSDt,
        unsigned short* __restrict__ h1b,
        float* __restrict__ ssrc1, float* __restrict__ sdst1, int M) {
    __shared__ unsigned short xb[64 * 128];    // gemm1 branch, 16KB
    __shared__ int sdeg[256];                  // csr branch
    __shared__ int scur[256];
    int t = threadIdx.x;
    if (blockIdx.x < NBUK) {
        // ---------------- per-bucket CSR (hidden under gemm1) --------------
        int b = blockIdx.x;
        int ebase = b * BCAP;
        int eend = ebase + bcursor[b];
        sdeg[t] = 0;
        __syncthreads();
        for (int i = ebase + t; i < eend; i += 256)
            atomicAdd(&sdeg[ebuf[i] >> 16], 1);
        __syncthreads();
        int x = sdeg[t];
        __syncthreads();
        for (int off = 1; off < 256; off <<= 1) {
            int v = (t >= off) ? sdeg[t - off] : 0;
            __syncthreads();
            sdeg[t] += v;
            __syncthreads();
        }
        int incl = sdeg[t];
        int excl = incl - x;
        int gnode = b * 256 + t;
        if (gnode < NN) {
            rowst[gnode] = ebase + excl;
            rowend[gnode] = ebase + incl;
        }
        scur[t] = excl;
        __syncthreads();
        for (int i = ebase + t; i < eend; i += 256) {
            unsigned int e = ebuf[i];
            int pos = atomicAdd(&scur[e >> 16], 1);
            srcs[ebase + pos] = (int)(e & 0xffffu);
        }
    } else {
        // ---------------- GEMM1 (MFMA bf16) + MFMA score fusion ------------
        int m0 = (blockIdx.x - NBUK) * 64;
#pragma unroll
        for (int r = 0; r < 8; ++r) {
            int f = r * 256 + t;
            int e = f * 4;
            int row = e >> 7, col = e & 127;
            float4 v = make_float4(0.f, 0.f, 0.f, 0.f);
            if (m0 + row < M) v = *(const float4*)&X[(size_t)(m0 + row) * 128 + col];
            ushort4 bb;
            bb.x = f2b(v.x); bb.y = f2b(v.y); bb.z = f2b(v.z); bb.w = f2b(v.w);
            *(ushort4*)((char*)xb + row * 256 + ((col * 2) ^ ((row & 7) << 4))) = bb;
        }
        __syncthreads();
        int wv = t >> 6, l = t & 63;
        int lm = l & 15, lk = l >> 4;
        int swz = (lm & 7) << 4;
        bf16x8 sfr[4];
#pragma unroll
        for (int kk = 0; kk < 4; ++kk)
            sfr[kk] = *(const bf16x8*)&waSDt[lm * 128 + kk * 32 + lk * 8];
        f32x4 acc[4][4];
        f32x4 accS[4];
#pragma unroll
        for (int a = 0; a < 4; ++a) {
            accS[a] = (f32x4){0.f, 0.f, 0.f, 0.f};
#pragma unroll
            for (int b2_ = 0; b2_ < 4; ++b2_) acc[a][b2_] = (f32x4){0.f, 0.f, 0.f, 0.f};
        }
#pragma unroll
        for (int kk = 0; kk < 4; ++kk) {
            int kb = (kk * 64 + lk * 16) ^ swz;
            bf16x8 af[4], bfr[4];
#pragma unroll
            for (int mf = 0; mf < 4; ++mf)
                af[mf] = *(const bf16x8*)((const char*)xb + (mf * 16 + lm) * 256 + kb);
#pragma unroll
            for (int nt = 0; nt < 4; ++nt)
                bfr[nt] = *(const bf16x8*)&w1t[(wv * 64 + nt * 16 + lm) * 128 + kk * 32 + lk * 8];
#pragma unroll
            for (int mf = 0; mf < 4; ++mf) {
#pragma unroll
                for (int nt = 0; nt < 4; ++nt)
                    acc[mf][nt] = __builtin_amdgcn_mfma_f32_16x16x32_bf16(af[mf], bfr[nt], acc[mf][nt], 0, 0, 0);
                accS[mf] = __builtin_amdgcn_mfma_f32_16x16x32_bf16(af[mf], sfr[kk], accS[mf], 0, 0, 0);
            }
        }
#pragma unroll
        for (int mf = 0; mf < 4; ++mf) {
#pragma unroll
            for (int r = 0; r < 4; ++r) {
                int row = m0 + mf * 16 + lk * 4 + r;
                if (row < M) {
#pragma unroll
                    for (int nt = 0; nt < 4; ++nt)
                        h1b[(size_t)row * 256 + wv * 64 + nt * 16 + lm] = f2b(acc[mf][nt][r]);
                }
            }
        }
        {
            f32x4 as = accS[wv];
#pragma unroll
            for (int r = 0; r < 4; ++r) {
                int row = m0 + wv * 16 + lk * 4 + r;
                if (row < M && lm < 8) {
                    if (lm < 4) ssrc1[row * HEADS + lm] = as[r];
                    else        sdst1[row * HEADS + (lm - 4)] = as[r];
                }
            }
        }
    }
}

// ------- fused layer-1: softmax (A, alpha->LDS) + gather/ELU (B) -----------
__global__ __launch_bounds__(256) void agg1_fused(const unsigned short* __restrict__ h1b,
                                                  const float* __restrict__ ssrc1,
                                                  const float* __restrict__ sdst1,
                                                  const int* __restrict__ rowst,
                                                  const int* __restrict__ rowend,
                                                  const int* __restrict__ srcs,
                                                  const float* __restrict__ b1,
                                                  unsigned short* __restrict__ out1b) {
    __shared__ float alds[4][64][4];   // [wave][edge][head], 4KB
    int wid = threadIdx.x >> 6;
    int d = blockIdx.x * 4 + wid;
    int l = threadIdx.x & 63;
    int start = rowst[d], end = rowend[d];
    int deg = end - start;

    // ---- phase A: per-head max+sum over 16 slots x 4 heads
    int sub = l & 15, h = l >> 4;
    float sdstA = sdst1[d * HEADS + h];
    auto comp = [&](int i) -> float {
        int s = srcs[i];
        float e = ssrc1[s * HEADS + h] + sdstA;
        return e > 0.f ? e : NEG_SLOPE * e;
    };
    float e0 = NEGINF, e1 = NEGINF, e2 = NEGINF, e3 = NEGINF;
    int i0 = start + sub;
    if (i0 < end) e0 = comp(i0);
    if (i0 + 16 < end) e1 = comp(i0 + 16);
    if (i0 + 32 < end) e2 = comp(i0 + 32);
    if (i0 + 48 < end) e3 = comp(i0 + 48);
    float mx = fmaxf(fmaxf(e0, e1), fmaxf(e2, e3));
    for (int i = i0 + 64; i < end; i += 16) mx = fmaxf(mx, comp(i));
#pragma unroll
    for (int o = 1; o < 16; o <<= 1) mx = fmaxf(mx, __shfl_xor(mx, o));
    float s0 = __expf(e0 - mx), s1 = __expf(e1 - mx);
    float s2 = __expf(e2 - mx), s3 = __expf(e3 - mx);
    float ssum = s0 + s1 + s2 + s3;
    for (int i = i0 + 64; i < end; i += 16) ssum += __expf(comp(i) - mx);
#pragma unroll
    for (int o = 1; o < 16; o <<= 1) ssum += __shfl_xor(ssum, o);
    float inv = 1.f / (ssum + EPS_SM);
    alds[wid][sub][h] = s0 * inv;
    alds[wid][sub + 16][h] = s1 * inv;
    alds[wid][sub + 32][h] = s2 * inv;
    alds[wid][sub + 48][h] = s3 * inv;

    // ---- phase B: gather, 2 edge-slots x 32 channel-lanes, 8-deep unroll
    int half = l >> 5;
    int cl = l & 31;
    int hc = cl >> 3;
    const int cb = cl * 8;
    float acc[8] = {};
    int i = start + half;
    if (deg <= 64) {
        // 8-deep: edges i, i+2, ..., i+14 (16 rows in flight per wave)
        for (; i + 14 < end; i += 16) {
            uint4 v[8];
            float a[8];
#pragma unroll
            for (int q = 0; q < 8; ++q) {
                int s = srcs[i + 2 * q];
                v[q] = *(const uint4*)&h1b[(size_t)s * C1 + cb];
            }
#pragma unroll
            for (int q = 0; q < 8; ++q) a[q] = alds[wid][i + 2 * q - start][hc];
#pragma unroll
            for (int q = 0; q < 8; ++q) {
                acc[0] += a[q] * b2f_lo(v[q].x); acc[1] += a[q] * b2f_hi(v[q].x);
                acc[2] += a[q] * b2f_lo(v[q].y); acc[3] += a[q] * b2f_hi(v[q].y);
                acc[4] += a[q] * b2f_lo(v[q].z); acc[5] += a[q] * b2f_hi(v[q].z);
                acc[6] += a[q] * b2f_lo(v[q].w); acc[7] += a[q] * b2f_hi(v[q].w);
            }
        }
        for (; i + 6 < end; i += 8) {
            uint4 v[4];
            float a[4];
#pragma unroll
            for (int q = 0; q < 4; ++q) {
                int s = srcs[i + 2 * q];
                v[q] = *(const uint4*)&h1b[(size_t)s * C1 + cb];
            }
#pragma unroll
            for (int q = 0; q < 4; ++q) a[q] = alds[wid][i + 2 * q - start][hc];
#pragma unroll
            for (int q = 0; q < 4; ++q) {
                acc[0] += a[q] * b2f_lo(v[q].x); acc[1] += a[q] * b2f_hi(v[q].x);
                acc[2] += a[q] * b2f_lo(v[q].y); acc[3] += a[q] * b2f_hi(v[q].y);
                acc[4] += a[q] * b2f_lo(v[q].z); acc[5] += a[q] * b2f_hi(v[q].z);
                acc[6] += a[q] * b2f_lo(v[q].w); acc[7] += a[q] * b2f_hi(v[q].w);
            }
        }
        for (; i < end; i += 2) {
            int s = srcs[i];
            uint4 v = *(const uint4*)&h1b[(size_t)s * C1 + cb];
            float a = alds[wid][i - start][hc];
            acc[0] += a * b2f_lo(v.x); acc[1] += a * b2f_hi(v.x);
            acc[2] += a * b2f_lo(v.y); acc[3] += a * b2f_hi(v.y);
            acc[4] += a * b2f_lo(v.z); acc[5] += a * b2f_hi(v.z);
            acc[6] += a * b2f_lo(v.w); acc[7] += a * b2f_hi(v.w);
        }
    } else {
        float mxB = __shfl(mx, hc << 4);
        float invB = __shfl(inv, hc << 4);
        float sdstB = __shfl(sdstA, hc << 4);
        for (; i < end; i += 2) {
            int s = srcs[i];
            uint4 v = *(const uint4*)&h1b[(size_t)s * C1 + cb];
            float e = ssrc1[s * HEADS + hc] + sdstB;
            e = e > 0.f ? e : NEG_SLOPE * e;
            float a = __expf(e - mxB) * invB;
            acc[0] += a * b2f_lo(v.x); acc[1] += a * b2f_hi(v.x);
            acc[2] += a * b2f_lo(v.y); acc[3] += a * b2f_hi(v.y);
            acc[4] += a * b2f_lo(v.z); acc[5] += a * b2f_hi(v.z);
            acc[6] += a * b2f_lo(v.w); acc[7] += a * b2f_hi(v.w);
        }
    }
#pragma unroll
    for (int j = 0; j < 8; ++j) acc[j] += __shfl_xor(acc[j], 32);
    if (half == 0) {
        float4 ba = *(const float4*)&b1[cb];
        float4 bbv = *(const float4*)&b1[cb + 4];
        float v[8];
        v[0] = acc[0] + ba.x;  v[1] = acc[1] + ba.y;
        v[2] = acc[2] + ba.z;  v[3] = acc[3] + ba.w;
        v[4] = acc[4] + bbv.x; v[5] = acc[5] + bbv.y;
        v[6] = acc[6] + bbv.z; v[7] = acc[7] + bbv.w;
        bf16x8 o;
#pragma unroll
        for (int j = 0; j < 8; ++j) {
            float t = v[j] > 0.f ? v[j] : (__expf(v[j]) - 1.f);
            o[j] = (short)f2b(t);
        }
        *(bf16x8*)&out1b[(size_t)d * C1 + cb] = o;
    }
}

// ------- GEMM2 (MFMA): h2[N,16] = out1b[N,256] @ W2b  + fused scores -------
__global__ __launch_bounds__(256) void gemm2_mfma(const unsigned short* __restrict__ out1b,
                                                  const unsigned short* __restrict__ w2b,
                                                  const float* __restrict__ a_src2,
                                                  const float* __restrict__ a_dst2,
                                                  float* __restrict__ h2,
                                                  float* __restrict__ ssrc2,
                                                  float* __restrict__ sdst2, int M) {
    __shared__ char ab[64 * 528];
    int tid = threadIdx.x;
    int m0 = blockIdx.x * 64;
#pragma unroll
    for (int r = 0; r < 8; ++r) {
        int byte = r * 4096 + tid * 16;
        int row = byte >> 9, col = byte & 511;
        uint4 v = make_uint4(0u, 0u, 0u, 0u);
        if (m0 + row < M)
            v = *(const uint4*)((const char*)out1b + (size_t)(m0 + row) * 512 + col);
        *(uint4*)(ab + row * 528 + col) = v;
    }
    int wv = tid >> 6, l = tid & 63;
    int lm = l & 15, lk = l >> 4;
    bf16x8 bfr[8];
#pragma unroll
    for (int kk = 0; kk < 8; ++kk)
        bfr[kk] = *(const bf16x8*)&w2b[lm * 256 + lk * 8 + kk * 32];
    __syncthreads();
    f32x4 acc = (f32x4){0.f, 0.f, 0.f, 0.f};
    const char* base = ab + (wv * 16 + lm) * 528 + lk * 16;
#pragma unroll
    for (int kk = 0; kk < 8; ++kk) {
        bf16x8 af = *(const bf16x8*)(base + kk * 64);
        acc = __builtin_amdgcn_mfma_f32_16x16x32_bf16(af, bfr[kk], acc, 0, 0, 0);
    }
    float asc = a_src2[lm], adc = a_dst2[lm];
#pragma unroll
    for (int r = 0; r < 4; ++r) {
        int grow = m0 + wv * 16 + lk * 4 + r;
        float v = acc[r];
        float ps = v * asc, pd = v * adc;
#pragma unroll
        for (int o = 1; o < 16; o <<= 1) {
            ps += __shfl_xor(ps, o);
            pd += __shfl_xor(pd, o);
        }
        if (grow < M) {
            h2[(size_t)grow * OUT_CH + lm] = v;
            if (lm == 0) {
                ssrc2[grow] = ps;
                sdst2[grow] = pd;
            }
        }
    }
}

// ------- fused layer-2: softmax (A, alpha->LDS) + gather + bias (B) --------
__global__ __launch_bounds__(256) void agg2_fused(const float* __restrict__ h2,
                                                  const float* __restrict__ ssrc2,
                                                  const float* __restrict__ sdst2,
                                                  const int* __restrict__ rowst,
                                                  const int* __restrict__ rowend,
                                                  const int* __restrict__ srcs,
                                                  const float* __restrict__ b2,
                                                  float* __restrict__ out) {
    __shared__ float alds[4][128];   // 2KB
    int wid = threadIdx.x >> 6;
    int d = blockIdx.x * 4 + wid;
    int l = threadIdx.x & 63;
    int start = rowst[d], end = rowend[d];
    int deg = end - start;
    float sdst = sdst2[d];
    auto comp = [&](int i) -> float {
        int s = srcs[i];
        float e = ssrc2[s] + sdst;
        return e > 0.f ? e : NEG_SLOPE * e;
    };
    float e0 = NEGINF, e1 = NEGINF;
    int i0 = start + l;
    if (i0 < end) e0 = comp(i0);
    if (i0 + 64 < end) e1 = comp(i0 + 64);
    float mx = fmaxf(e0, e1);
    for (int i = i0 + 128; i < end; i += 64) mx = fmaxf(mx, comp(i));
#pragma unroll
    for (int o = 1; o < 64; o <<= 1) mx = fmaxf(mx, __shfl_xor(mx, o));
    float s0 = __expf(e0 - mx), s1 = __expf(e1 - mx);
    float ssum = s0 + s1;
    for (int i = i0 + 128; i < end; i += 64) ssum += __expf(comp(i) - mx);
#pragma unroll
    for (int o = 1; o < 64; o <<= 1) ssum += __shfl_xor(ssum, o);
    float inv = 1.f / (ssum + EPS_SM);
    alds[wid][l] = s0 * inv;
    alds[wid][l + 64] = s1 * inv;

    int slot = l >> 2;
    int c4 = (l & 3) * 4;
    float4 acc = make_float4(0.f, 0.f, 0.f, 0.f);
    if (deg <= 128) {
        for (int i = start + slot; i < end; i += 16) {
            int s = srcs[i];
            float a = alds[wid][i - start];
            float4 v = *(const float4*)&h2[(size_t)s * OUT_CH + c4];
            acc.x += a * v.x; acc.y += a * v.y; acc.z += a * v.z; acc.w += a * v.w;
        }
    } else {
        for (int i = start + slot; i < end; i += 16) {
            int s = srcs[i];
            float e = ssrc2[s] + sdst;
            e = e > 0.f ? e : NEG_SLOPE * e;
            float a = __expf(e - mx) * inv;
            float4 v = *(const float4*)&h2[(size_t)s * OUT_CH + c4];
            acc.x += a * v.x; acc.y += a * v.y; acc.z += a * v.z; acc.w += a * v.w;
        }
    }
#pragma unroll
    for (int o = 4; o < 64; o <<= 1) {
        acc.x += __shfl_xor(acc.x, o);
        acc.y += __shfl_xor(acc.y, o);
        acc.z += __shfl_xor(acc.z, o);
        acc.w += __shfl_xor(acc.w, o);
    }
    if (l < 4) {
        float4 bb = *(const float4*)&b2[c4];
        float4 r = make_float4(acc.x + bb.x, acc.y + bb.y, acc.z + bb.z, acc.w + bb.w);
        *(float4*)&out[(size_t)d * OUT_CH + c4] = r;
    }
}

extern "C" void kernel_launch(void* const* d_in, const int* in_sizes, int n_in,
                              void* d_out, int out_size, void* d_ws, size_t ws_size,
                              hipStream_t stream) {
    const float* x      = (const float*)d_in[0];
    const int*   ei     = (const int*)d_in[1];
    const float* W1     = (const float*)d_in[2];
    const float* a_src1 = (const float*)d_in[3];
    const float* a_dst1 = (const float*)d_in[4];
    const float* b1     = (const float*)d_in[5];
    const float* W2     = (const float*)d_in[6];
    const float* a_src2 = (const float*)d_in[7];
    const float* a_dst2 = (const float*)d_in[8];
    const float* b2     = (const float*)d_in[9];
    float* out = (float*)d_out;

    const int E = in_sizes[1] / 2;
    const int Etot = E + NN;
    const int* src_arr = ei;
    const int* dst_arr = ei + E;

    size_t off = 0;
    auto carve = [&](size_t bytes) -> void* {
        void* r = (char*)d_ws + off;
        off += (bytes + 255) & ~(size_t)255;
        return r;
    };
    unsigned short* h1b  = (unsigned short*)carve((size_t)NN * C1 * 2);
    unsigned short* out1b= (unsigned short*)carve((size_t)NN * C1 * 2);
    unsigned short* w1t  = (unsigned short*)carve((size_t)IN_CH * C1 * 2);
    unsigned short* w2b  = (unsigned short*)carve((size_t)C1 * OUT_CH * 2);
    unsigned short* waSDt= (unsigned short*)carve((size_t)16 * 128 * 2);
    float* ssrc1 = (float*)carve((size_t)NN * HEADS * 4);
    float* sdst1 = (float*)carve((size_t)NN * HEADS * 4);
    float* h2    = (float*)carve((size_t)NN * OUT_CH * 4);
    float* ssrc2 = (float*)carve((size_t)NN * 4);
    float* sdst2 = (float*)carve((size_t)NN * 4);
    int* rowst   = (int*)carve((size_t)NN * 4);
    int* rowend  = (int*)carve((size_t)NN * 4);
    int* srcs    = (int*)carve((size_t)NBUK * BCAP * 4);
    unsigned int* ebuf = (unsigned int*)carve((size_t)NBUK * BCAP * 4);
    int* bcursor = (int*)carve((size_t)NBUK * 4);

    // ---- launch 1: zero bucket counters (bases are static b*BCAP) ----
    hipMemsetAsync(bcursor, 0, (size_t)NBUK * 4, stream);
    // ---- launch 2: bucket_scatter ∥ cvt_weights ----
    fused_scatter_cvt<<<256 + 145, 256, 0, stream>>>(src_arr, dst_arr, bcursor, ebuf,
                                                     Etot, E, W1, W2, a_src1, a_dst1,
                                                     w1t, w2b, waSDt);
    // ---- launch 3: bucket_csr ∥ gemm1 ----
    fused_csr_gemm1<<<NBUK + NGEMM1, 256, 0, stream>>>(ebuf, bcursor,
                                                       rowst, rowend, srcs,
                                                       x, w1t, waSDt,
                                                       h1b, ssrc1, sdst1, NN);
    // ---- launch 4: layer-1 softmax+aggregate ----
    agg1_fused<<<NN / 4, 256, 0, stream>>>(h1b, ssrc1, sdst1, rowst, rowend, srcs,
                                           b1, out1b);
    // ---- launch 5: layer-2 GEMM ----
    gemm2_mfma<<<NGEMM1, 256, 0, stream>>>(out1b, w2b, a_src2, a_dst2,
                                           h2, ssrc2, sdst2, NN);
    // ---- launch 6: layer-2 softmax+aggregate ----
    agg2_fused<<<NN / 4, 256, 0, stream>>>(h2, ssrc2, sdst2, rowst, rowend, srcs,
                                           b2, out);
}

// Round 14
// 149.000 us; speedup vs baseline: 1.0325x; 1.0325x over previous
//
#include <hip/hip_runtime.h>
#include <cstdint>
#include <cstddef>

#define NN 50000
#define IN_CH 128
#define C1 256        // HEADS*HID
#define HID 64
#define HEADS 4
#define OUT_CH 16
#define NEG_SLOPE 0.2f
#define EPS_SM 1e-16f
#define NEGINF -3.4e38f
#define NBUK ((NN + 255) >> 8)   // 196 buckets of 256 dst nodes
#define BCAP 4864                // bucket capacity: mean 4352 + 8 sigma
#define NGEMM1 ((NN + 63) / 64)  // 782

typedef __attribute__((ext_vector_type(8))) short bf16x8;
typedef __attribute__((ext_vector_type(4))) float f32x4;

__device__ __forceinline__ unsigned short f2b(float f) {
    unsigned int u = __float_as_uint(f);
    u += 0x7fffu + ((u >> 16) & 1u);   // round-to-nearest-even
    return (unsigned short)(u >> 16);
}
__device__ __forceinline__ float b2f_lo(unsigned int packed) {
    return __uint_as_float(packed << 16);
}
__device__ __forceinline__ float b2f_hi(unsigned int packed) {
    return __uint_as_float(packed & 0xffff0000u);
}

// ===== launch 2: bucket_scatter (blocks 0..255) ∥ cvt_weights (256..400) ====
__global__ __launch_bounds__(256) void fused_scatter_cvt(
        const int* __restrict__ src_arr, const int* __restrict__ dst_arr,
        int* __restrict__ bcursor, unsigned int* __restrict__ ebuf,
        int Etot, int E,
        const float* __restrict__ W1, const float* __restrict__ W2,
        const float* __restrict__ a_src1, const float* __restrict__ a_dst1,
        unsigned short* __restrict__ w1t, unsigned short* __restrict__ w2b,
        unsigned short* __restrict__ waSDt) {
    __shared__ int cnt[NBUK];
    __shared__ int cur[NBUK];
    int t = threadIdx.x;
    if (blockIdx.x < 256) {
        int bid = blockIdx.x;
        for (int i = t; i < NBUK; i += 256) cnt[i] = 0;
        __syncthreads();
        for (int i = bid * 256 + t; i < Etot; i += 65536) {
            int dst = (i < E) ? dst_arr[i] : (i - E);
            atomicAdd(&cnt[dst >> 8], 1);
        }
        __syncthreads();
        for (int i = t; i < NBUK; i += 256)
            cur[i] = i * BCAP + (cnt[i] ? atomicAdd(&bcursor[i], cnt[i]) : 0);
        __syncthreads();
        for (int i = bid * 256 + t; i < Etot; i += 65536) {
            int dst, src;
            if (i < E) { dst = dst_arr[i]; src = src_arr[i]; }
            else { dst = i - E; src = i - E; }
            int buk = dst >> 8;
            int pos = atomicAdd(&cur[buk], 1);
            if (pos < (buk + 1) * BCAP)   // 8-sigma guard, never expected
                ebuf[pos] = ((unsigned int)(dst & 255) << 16) | (unsigned int)src;
        }
    } else {
        int b = blockIdx.x - 256;
        if (b < 128) {
            w1t[t * 128 + b] = f2b(W1[b * 256 + t]);
        } else if (b < 144) {
            int k = (b - 128) * 16 + (t >> 4);
            int c = t & 15;
            w2b[c * 256 + k] = f2b(W2[k * 16 + c]);
        } else {
            if (t < 128) {
                const float* wrow = W1 + t * 256;
#pragma unroll
                for (int h = 0; h < 4; ++h) {
                    float ss = 0.f, sd = 0.f;
#pragma unroll
                    for (int c = 0; c < 64; ++c) {
                        float w = wrow[h * 64 + c];
                        ss += w * a_src1[h * 64 + c];
                        sd += w * a_dst1[h * 64 + c];
                    }
                    waSDt[h * 128 + t] = f2b(ss);
                    waSDt[(4 + h) * 128 + t] = f2b(sd);
                }
#pragma unroll
                for (int c = 8; c < 16; ++c) waSDt[c * 128 + t] = 0;
            }
        }
    }
}

// ===== launch 3: bucket_csr (blocks 0..195) ∥ gemm1 (196..977) ==============
__global__ __launch_bounds__(256) void fused_csr_gemm1(
        const unsigned int* __restrict__ ebuf, const int* __restrict__ bcursor,
        int* __restrict__ rowst, int* __restrict__ rowend, int* __restrict__ srcs,
        const float* __restrict__ X,
        const unsigned short* __restrict__ w1t,
        const unsigned short* __restrict__ waSDt,
        unsigned short* __restrict__ h1b,
        float* __restrict__ ssrc1, float* __restrict__ sdst1, int M) {
    __shared__ unsigned short xb[64 * 128];    // gemm1 branch, 16KB
    __shared__ int sdeg[256];                  // csr branch
    __shared__ int scur[256];
    int t = threadIdx.x;
    if (blockIdx.x < NBUK) {
        int b = blockIdx.x;
        int ebase = b * BCAP;
        int eend = ebase + bcursor[b];
        sdeg[t] = 0;
        __syncthreads();
        for (int i = ebase + t; i < eend; i += 256)
            atomicAdd(&sdeg[ebuf[i] >> 16], 1);
        __syncthreads();
        int x = sdeg[t];
        __syncthreads();
        for (int off = 1; off < 256; off <<= 1) {
            int v = (t >= off) ? sdeg[t - off] : 0;
            __syncthreads();
            sdeg[t] += v;
            __syncthreads();
        }
        int incl = sdeg[t];
        int excl = incl - x;
        int gnode = b * 256 + t;
        if (gnode < NN) {
            rowst[gnode] = ebase + excl;
            rowend[gnode] = ebase + incl;
        }
        scur[t] = excl;
        __syncthreads();
        for (int i = ebase + t; i < eend; i += 256) {
            unsigned int e = ebuf[i];
            int pos = atomicAdd(&scur[e >> 16], 1);
            srcs[ebase + pos] = (int)(e & 0xffffu);
        }
    } else {
        int m0 = (blockIdx.x - NBUK) * 64;
#pragma unroll
        for (int r = 0; r < 8; ++r) {
            int f = r * 256 + t;
            int e = f * 4;
            int row = e >> 7, col = e & 127;
            float4 v = make_float4(0.f, 0.f, 0.f, 0.f);
            if (m0 + row < M) v = *(const float4*)&X[(size_t)(m0 + row) * 128 + col];
            ushort4 bb;
            bb.x = f2b(v.x); bb.y = f2b(v.y); bb.z = f2b(v.z); bb.w = f2b(v.w);
            *(ushort4*)((char*)xb + row * 256 + ((col * 2) ^ ((row & 7) << 4))) = bb;
        }
        __syncthreads();
        int wv = t >> 6, l = t & 63;
        int lm = l & 15, lk = l >> 4;
        int swz = (lm & 7) << 4;
        bf16x8 sfr[4];
#pragma unroll
        for (int kk = 0; kk < 4; ++kk)
            sfr[kk] = *(const bf16x8*)&waSDt[lm * 128 + kk * 32 + lk * 8];
        f32x4 acc[4][4];
        f32x4 accS[4];
#pragma unroll
        for (int a = 0; a < 4; ++a) {
            accS[a] = (f32x4){0.f, 0.f, 0.f, 0.f};
#pragma unroll
            for (int b2_ = 0; b2_ < 4; ++b2_) acc[a][b2_] = (f32x4){0.f, 0.f, 0.f, 0.f};
        }
#pragma unroll
        for (int kk = 0; kk < 4; ++kk) {
            int kb = (kk * 64 + lk * 16) ^ swz;
            bf16x8 af[4], bfr[4];
#pragma unroll
            for (int mf = 0; mf < 4; ++mf)
                af[mf] = *(const bf16x8*)((const char*)xb + (mf * 16 + lm) * 256 + kb);
#pragma unroll
            for (int nt = 0; nt < 4; ++nt)
                bfr[nt] = *(const bf16x8*)&w1t[(wv * 64 + nt * 16 + lm) * 128 + kk * 32 + lk * 8];
#pragma unroll
            for (int mf = 0; mf < 4; ++mf) {
#pragma unroll
                for (int nt = 0; nt < 4; ++nt)
                    acc[mf][nt] = __builtin_amdgcn_mfma_f32_16x16x32_bf16(af[mf], bfr[nt], acc[mf][nt], 0, 0, 0);
                accS[mf] = __builtin_amdgcn_mfma_f32_16x16x32_bf16(af[mf], sfr[kk], accS[mf], 0, 0, 0);
            }
        }
#pragma unroll
        for (int mf = 0; mf < 4; ++mf) {
#pragma unroll
            for (int r = 0; r < 4; ++r) {
                int row = m0 + mf * 16 + lk * 4 + r;
                if (row < M) {
#pragma unroll
                    for (int nt = 0; nt < 4; ++nt)
                        h1b[(size_t)row * 256 + wv * 64 + nt * 16 + lm] = f2b(acc[mf][nt][r]);
                }
            }
        }
        {
            f32x4 as = accS[wv];
#pragma unroll
            for (int r = 0; r < 4; ++r) {
                int row = m0 + wv * 16 + lk * 4 + r;
                if (row < M && lm < 8) {
                    if (lm < 4) ssrc1[row * HEADS + lm] = as[r];
                    else        sdst1[row * HEADS + (lm - 4)] = as[r];
                }
            }
        }
    }
}

// ------- fused layer-1: softmax (A, alpha->LDS) + gather/ELU (B) -----------
// Phase B: exact R12 4-deep form (best measured: 67.5 us).
__global__ __launch_bounds__(256) void agg1_fused(const unsigned short* __restrict__ h1b,
                                                  const float* __restrict__ ssrc1,
                                                  const float* __restrict__ sdst1,
                                                  const int* __restrict__ rowst,
                                                  const int* __restrict__ rowend,
                                                  const int* __restrict__ srcs,
                                                  const float* __restrict__ b1,
                                                  unsigned short* __restrict__ out1b) {
    __shared__ float alds[4][64][4];   // [wave][edge][head], 4KB
    int wid = threadIdx.x >> 6;
    int d = blockIdx.x * 4 + wid;
    int l = threadIdx.x & 63;
    int start = rowst[d], end = rowend[d];
    int deg = end - start;

    // ---- phase A: per-head max+sum over 16 slots x 4 heads
    int sub = l & 15, h = l >> 4;
    float sdstA = sdst1[d * HEADS + h];
    auto comp = [&](int i) -> float {
        int s = srcs[i];
        float e = ssrc1[s * HEADS + h] + sdstA;
        return e > 0.f ? e : NEG_SLOPE * e;
    };
    float e0 = NEGINF, e1 = NEGINF, e2 = NEGINF, e3 = NEGINF;
    int i0 = start + sub;
    if (i0 < end) e0 = comp(i0);
    if (i0 + 16 < end) e1 = comp(i0 + 16);
    if (i0 + 32 < end) e2 = comp(i0 + 32);
    if (i0 + 48 < end) e3 = comp(i0 + 48);
    float mx = fmaxf(fmaxf(e0, e1), fmaxf(e2, e3));
    for (int i = i0 + 64; i < end; i += 16) mx = fmaxf(mx, comp(i));
#pragma unroll
    for (int o = 1; o < 16; o <<= 1) mx = fmaxf(mx, __shfl_xor(mx, o));
    float s0 = __expf(e0 - mx), s1 = __expf(e1 - mx);
    float s2 = __expf(e2 - mx), s3 = __expf(e3 - mx);
    float ssum = s0 + s1 + s2 + s3;
    for (int i = i0 + 64; i < end; i += 16) ssum += __expf(comp(i) - mx);
#pragma unroll
    for (int o = 1; o < 16; o <<= 1) ssum += __shfl_xor(ssum, o);
    float inv = 1.f / (ssum + EPS_SM);
    alds[wid][sub][h] = s0 * inv;
    alds[wid][sub + 16][h] = s1 * inv;
    alds[wid][sub + 32][h] = s2 * inv;
    alds[wid][sub + 48][h] = s3 * inv;

    // ---- phase B: gather, 2 edge-slots x 32 channel-lanes, 4-deep unroll
    int half = l >> 5;
    int cl = l & 31;
    int hc = cl >> 3;
    const int cb = cl * 8;
    float acc[8] = {};
    int i = start + half;
    if (deg <= 64) {
        for (; i + 6 < end; i += 8) {
            int s0_ = srcs[i], s1_ = srcs[i + 2], s2_ = srcs[i + 4], s3_ = srcs[i + 6];
            uint4 v0 = *(const uint4*)&h1b[(size_t)s0_ * C1 + cb];
            uint4 v1 = *(const uint4*)&h1b[(size_t)s1_ * C1 + cb];
            uint4 v2 = *(const uint4*)&h1b[(size_t)s2_ * C1 + cb];
            uint4 v3 = *(const uint4*)&h1b[(size_t)s3_ * C1 + cb];
            float a0 = alds[wid][i - start][hc];
            float a1 = alds[wid][i + 2 - start][hc];
            float a2 = alds[wid][i + 4 - start][hc];
            float a3 = alds[wid][i + 6 - start][hc];
            acc[0] += a0 * b2f_lo(v0.x) + a1 * b2f_lo(v1.x) + a2 * b2f_lo(v2.x) + a3 * b2f_lo(v3.x);
            acc[1] += a0 * b2f_hi(v0.x) + a1 * b2f_hi(v1.x) + a2 * b2f_hi(v2.x) + a3 * b2f_hi(v3.x);
            acc[2] += a0 * b2f_lo(v0.y) + a1 * b2f_lo(v1.y) + a2 * b2f_lo(v2.y) + a3 * b2f_lo(v3.y);
            acc[3] += a0 * b2f_hi(v0.y) + a1 * b2f_hi(v1.y) + a2 * b2f_hi(v2.y) + a3 * b2f_hi(v3.y);
            acc[4] += a0 * b2f_lo(v0.z) + a1 * b2f_lo(v1.z) + a2 * b2f_lo(v2.z) + a3 * b2f_lo(v3.z);
            acc[5] += a0 * b2f_hi(v0.z) + a1 * b2f_hi(v1.z) + a2 * b2f_hi(v2.z) + a3 * b2f_hi(v3.z);
            acc[6] += a0 * b2f_lo(v0.w) + a1 * b2f_lo(v1.w) + a2 * b2f_lo(v2.w) + a3 * b2f_lo(v3.w);
            acc[7] += a0 * b2f_hi(v0.w) + a1 * b2f_hi(v1.w) + a2 * b2f_hi(v2.w) + a3 * b2f_hi(v3.w);
        }
        for (; i < end; i += 2) {
            int s = srcs[i];
            uint4 v = *(const uint4*)&h1b[(size_t)s * C1 + cb];
            float a = alds[wid][i - start][hc];
            acc[0] += a * b2f_lo(v.x); acc[1] += a * b2f_hi(v.x);
            acc[2] += a * b2f_lo(v.y); acc[3] += a * b2f_hi(v.y);
            acc[4] += a * b2f_lo(v.z); acc[5] += a * b2f_hi(v.z);
            acc[6] += a * b2f_lo(v.w); acc[7] += a * b2f_hi(v.w);
        }
    } else {
        float mxB = __shfl(mx, hc << 4);
        float invB = __shfl(inv, hc << 4);
        float sdstB = __shfl(sdstA, hc << 4);
        for (; i < end; i += 2) {
            int s = srcs[i];
            uint4 v = *(const uint4*)&h1b[(size_t)s * C1 + cb];
            float e = ssrc1[s * HEADS + hc] + sdstB;
            e = e > 0.f ? e : NEG_SLOPE * e;
            float a = __expf(e - mxB) * invB;
            acc[0] += a * b2f_lo(v.x); acc[1] += a * b2f_hi(v.x);
            acc[2] += a * b2f_lo(v.y); acc[3] += a * b2f_hi(v.y);
            acc[4] += a * b2f_lo(v.z); acc[5] += a * b2f_hi(v.z);
            acc[6] += a * b2f_lo(v.w); acc[7] += a * b2f_hi(v.w);
        }
    }
#pragma unroll
    for (int j = 0; j < 8; ++j) acc[j] += __shfl_xor(acc[j], 32);
    if (half == 0) {
        float4 ba = *(const float4*)&b1[cb];
        float4 bbv = *(const float4*)&b1[cb + 4];
        float v[8];
        v[0] = acc[0] + ba.x;  v[1] = acc[1] + ba.y;
        v[2] = acc[2] + ba.z;  v[3] = acc[3] + ba.w;
        v[4] = acc[4] + bbv.x; v[5] = acc[5] + bbv.y;
        v[6] = acc[6] + bbv.z; v[7] = acc[7] + bbv.w;
        bf16x8 o;
#pragma unroll
        for (int j = 0; j < 8; ++j) {
            float t = v[j] > 0.f ? v[j] : (__expf(v[j]) - 1.f);
            o[j] = (short)f2b(t);
        }
        *(bf16x8*)&out1b[(size_t)d * C1 + cb] = o;
    }
}

// ------- GEMM2 (MFMA): h2b[N,16] bf16 = out1b @ W2b + fused scores ---------
__global__ __launch_bounds__(256) void gemm2_mfma(const unsigned short* __restrict__ out1b,
                                                  const unsigned short* __restrict__ w2b,
                                                  const float* __restrict__ a_src2,
                                                  const float* __restrict__ a_dst2,
                                                  unsigned short* __restrict__ h2b,
                                                  float* __restrict__ ssrc2,
                                                  float* __restrict__ sdst2, int M) {
    __shared__ char ab[64 * 528];
    int tid = threadIdx.x;
    int m0 = blockIdx.x * 64;
#pragma unroll
    for (int r = 0; r < 8; ++r) {
        int byte = r * 4096 + tid * 16;
        int row = byte >> 9, col = byte & 511;
        uint4 v = make_uint4(0u, 0u, 0u, 0u);
        if (m0 + row < M)
            v = *(const uint4*)((const char*)out1b + (size_t)(m0 + row) * 512 + col);
        *(uint4*)(ab + row * 528 + col) = v;
    }
    int wv = tid >> 6, l = tid & 63;
    int lm = l & 15, lk = l >> 4;
    bf16x8 bfr[8];
#pragma unroll
    for (int kk = 0; kk < 8; ++kk)
        bfr[kk] = *(const bf16x8*)&w2b[lm * 256 + lk * 8 + kk * 32];
    __syncthreads();
    f32x4 acc = (f32x4){0.f, 0.f, 0.f, 0.f};
    const char* base = ab + (wv * 16 + lm) * 528 + lk * 16;
#pragma unroll
    for (int kk = 0; kk < 8; ++kk) {
        bf16x8 af = *(const bf16x8*)(base + kk * 64);
        acc = __builtin_amdgcn_mfma_f32_16x16x32_bf16(af, bfr[kk], acc, 0, 0, 0);
    }
    float asc = a_src2[lm], adc = a_dst2[lm];
#pragma unroll
    for (int r = 0; r < 4; ++r) {
        int grow = m0 + wv * 16 + lk * 4 + r;
        float v = acc[r];
        float ps = v * asc, pd = v * adc;
#pragma unroll
        for (int o = 1; o < 16; o <<= 1) {
            ps += __shfl_xor(ps, o);
            pd += __shfl_xor(pd, o);
        }
        if (grow < M) {
            h2b[(size_t)grow * OUT_CH + lm] = f2b(v);
            if (lm == 0) {
                ssrc2[grow] = ps;
                sdst2[grow] = pd;
            }
        }
    }
}

// ------- fused layer-2: softmax (A, alpha->LDS) + bf16 gather + bias (B) ---
__global__ __launch_bounds__(256) void agg2_fused(const unsigned short* __restrict__ h2b,
                                                  const float* __restrict__ ssrc2,
                                                  const float* __restrict__ sdst2,
                                                  const int* __restrict__ rowst,
                                                  const int* __restrict__ rowend,
                                                  const int* __restrict__ srcs,
                                                  const float* __restrict__ b2,
                                                  float* __restrict__ out) {
    __shared__ float alds[4][128];   // 2KB
    int wid = threadIdx.x >> 6;
    int d = blockIdx.x * 4 + wid;
    int l = threadIdx.x & 63;
    int start = rowst[d], end = rowend[d];
    int deg = end - start;
    float sdst = sdst2[d];
    auto comp = [&](int i) -> float {
        int s = srcs[i];
        float e = ssrc2[s] + sdst;
        return e > 0.f ? e : NEG_SLOPE * e;
    };
    float e0 = NEGINF, e1 = NEGINF;
    int i0 = start + l;
    if (i0 < end) e0 = comp(i0);
    if (i0 + 64 < end) e1 = comp(i0 + 64);
    float mx = fmaxf(e0, e1);
    for (int i = i0 + 128; i < end; i += 64) mx = fmaxf(mx, comp(i));
#pragma unroll
    for (int o = 1; o < 64; o <<= 1) mx = fmaxf(mx, __shfl_xor(mx, o));
    float s0 = __expf(e0 - mx), s1 = __expf(e1 - mx);
    float ssum = s0 + s1;
    for (int i = i0 + 128; i < end; i += 64) ssum += __expf(comp(i) - mx);
#pragma unroll
    for (int o = 1; o < 64; o <<= 1) ssum += __shfl_xor(ssum, o);
    float inv = 1.f / (ssum + EPS_SM);
    alds[wid][l] = s0 * inv;
    alds[wid][l + 64] = s1 * inv;

    int slot = l >> 2;
    int c4 = (l & 3) * 4;
    float4 acc = make_float4(0.f, 0.f, 0.f, 0.f);
    if (deg <= 128) {
        for (int i = start + slot; i < end; i += 16) {
            int s = srcs[i];
            float a = alds[wid][i - start];
            uint2 v = *(const uint2*)&h2b[(size_t)s * OUT_CH + c4];
            acc.x += a * b2f_lo(v.x); acc.y += a * b2f_hi(v.x);
            acc.z += a * b2f_lo(v.y); acc.w += a * b2f_hi(v.y);
        }
    } else {
        for (int i = start + slot; i < end; i += 16) {
            int s = srcs[i];
            float e = ssrc2[s] + sdst;
            e = e > 0.f ? e : NEG_SLOPE * e;
            float a = __expf(e - mx) * inv;
            uint2 v = *(const uint2*)&h2b[(size_t)s * OUT_CH + c4];
            acc.x += a * b2f_lo(v.x); acc.y += a * b2f_hi(v.x);
            acc.z += a * b2f_lo(v.y); acc.w += a * b2f_hi(v.y);
        }
    }
#pragma unroll
    for (int o = 4; o < 64; o <<= 1) {
        acc.x += __shfl_xor(acc.x, o);
        acc.y += __shfl_xor(acc.y, o);
        acc.z += __shfl_xor(acc.z, o);
        acc.w += __shfl_xor(acc.w, o);
    }
    if (l < 4) {
        float4 bb = *(const float4*)&b2[c4];
        float4 r = make_float4(acc.x + bb.x, acc.y + bb.y, acc.z + bb.z, acc.w + bb.w);
        *(float4*)&out[(size_t)d * OUT_CH + c4] = r;
    }
}

extern "C" void kernel_launch(void* const* d_in, const int* in_sizes, int n_in,
                              void* d_out, int out_size, void* d_ws, size_t ws_size,
                              hipStream_t stream) {
    const float* x      = (const float*)d_in[0];
    const int*   ei     = (const int*)d_in[1];
    const float* W1     = (const float*)d_in[2];
    const float* a_src1 = (const float*)d_in[3];
    const float* a_dst1 = (const float*)d_in[4];
    const float* b1     = (const float*)d_in[5];
    const float* W2     = (const float*)d_in[6];
    const float* a_src2 = (const float*)d_in[7];
    const float* a_dst2 = (const float*)d_in[8];
    const float* b2     = (const float*)d_in[9];
    float* out = (float*)d_out;

    const int E = in_sizes[1] / 2;
    const int Etot = E + NN;
    const int* src_arr = ei;
    const int* dst_arr = ei + E;

    size_t off = 0;
    auto carve = [&](size_t bytes) -> void* {
        void* r = (char*)d_ws + off;
        off += (bytes + 255) & ~(size_t)255;
        return r;
    };
    unsigned short* h1b  = (unsigned short*)carve((size_t)NN * C1 * 2);
    unsigned short* out1b= (unsigned short*)carve((size_t)NN * C1 * 2);
    unsigned short* w1t  = (unsigned short*)carve((size_t)IN_CH * C1 * 2);
    unsigned short* w2b  = (unsigned short*)carve((size_t)C1 * OUT_CH * 2);
    unsigned short* waSDt= (unsigned short*)carve((size_t)16 * 128 * 2);
    float* ssrc1 = (float*)carve((size_t)NN * HEADS * 4);
    float* sdst1 = (float*)carve((size_t)NN * HEADS * 4);
    unsigned short* h2b = (unsigned short*)carve((size_t)NN * OUT_CH * 2);
    float* ssrc2 = (float*)carve((size_t)NN * 4);
    float* sdst2 = (float*)carve((size_t)NN * 4);
    int* rowst   = (int*)carve((size_t)NN * 4);
    int* rowend  = (int*)carve((size_t)NN * 4);
    int* srcs    = (int*)carve((size_t)NBUK * BCAP * 4);
    unsigned int* ebuf = (unsigned int*)carve((size_t)NBUK * BCAP * 4);
    int* bcursor = (int*)carve((size_t)NBUK * 4);

    // ---- launch 1: zero bucket counters (bases are static b*BCAP) ----
    hipMemsetAsync(bcursor, 0, (size_t)NBUK * 4, stream);
    // ---- launch 2: bucket_scatter ∥ cvt_weights ----
    fused_scatter_cvt<<<256 + 145, 256, 0, stream>>>(src_arr, dst_arr, bcursor, ebuf,
                                                     Etot, E, W1, W2, a_src1, a_dst1,
                                                     w1t, w2b, waSDt);
    // ---- launch 3: bucket_csr ∥ gemm1 ----
    fused_csr_gemm1<<<NBUK + NGEMM1, 256, 0, stream>>>(ebuf, bcursor,
                                                       rowst, rowend, srcs,
                                                       x, w1t, waSDt,
                                                       h1b, ssrc1, sdst1, NN);
    // ---- launch 4: layer-1 softmax+aggregate ----
    agg1_fused<<<NN / 4, 256, 0, stream>>>(h1b, ssrc1, sdst1, rowst, rowend, srcs,
                                           b1, out1b);
    // ---- launch 5: layer-2 GEMM ----
    gemm2_mfma<<<NGEMM1, 256, 0, stream>>>(out1b, w2b, a_src2, a_dst2,
                                           h2b, ssrc2, sdst2, NN);
    // ---- launch 6: layer-2 softmax+aggregate ----
    agg2_fused<<<NN / 4, 256, 0, stream>>>(h2b, ssrc2, sdst2, rowst, rowend, srcs,
                                           b2, out);
}